// Round 9
// baseline (6313.205 us; speedup 1.0000x reference)
//
#include <hip/hip_runtime.h>
#include <hip/hip_cooperative_groups.h>

namespace cg = cooperative_groups;
typedef unsigned long long u64;

#define G    128
#define GG   (G * G)
#define P    130
#define P2   (P * P)
#define NPAD (P * P * P)        // 2,197,000
#define NG   (G * G * G)        // 2,097,152
#define NB   512
#define NT   256
#define TOT  (NB * NT)          // 131,072
#define CH   (NG / NB)          // 4096 cells per block (quarter-plane slab, 32 j-rows)
#define SEG  768                // per-block per-color list capacity (mean 512, 13 sigma)
#define NLEAD 8
#define NCH   (NB / NLEAD)      // 64 children per leader

// device-scope (MALL-coherent, L1/L2-bypassing) accesses for all loop-shared data
__device__ inline float LDV(const float* p) {
    return __hip_atomic_load((float*)p, __ATOMIC_RELAXED, __HIP_MEMORY_SCOPE_AGENT);
}
__device__ inline void STV(float* p, float x) {
    __hip_atomic_store(p, x, __ATOMIC_RELAXED, __HIP_MEMORY_SCOPE_AGENT);
}
__device__ inline u64 LDF(const u64* p) {
    return __hip_atomic_load((u64*)p, __ATOMIC_RELAXED, __HIP_MEMORY_SCOPE_AGENT);
}

// block reduce: wave64 shuffle + 4-slot LDS combine (deterministic fixed order)
__device__ inline float bred(float x, int t, float* s4) {
    for (int o = 32; o; o >>= 1) x += __shfl_down(x, o, 64);
    __syncthreads();
    if ((t & 63) == 0) s4[t >> 6] = x;
    __syncthreads();
    return ((s4[0] + s4[1]) + s4[2]) + s4[3];
}

// two-level payload barrier (proven round 8). leaf = (phase<<32)|bits(partial),
// slot by phase parity. Leaders (b<8) poll 64 children 1-load/lane, shfl-sum
// (fixed order), publish to lead flag; all blocks poll the 8 lead flags (one
// 64B line) and return the fixed-order global sum; identical in every block.
__device__ inline float gbar2(u64* __restrict__ leaf, u64* __restrict__ lead,
                              int phase, int b, int t, float part) {
    asm volatile("s_waitcnt vmcnt(0)" ::: "memory");  // drain this wave's stores
    __syncthreads();                                  // all waves drained
    const int slot = phase & 1;
    if (t == 0) {
        u64 w = ((u64)(unsigned)phase << 32) | (u64)__float_as_uint(part);
        __hip_atomic_store(&leaf[slot * NB + b], w, __ATOMIC_RELAXED,
                           __HIP_MEMORY_SCOPE_AGENT);
    }
    float lsum = 0.0f;
    if (t < 64) {
        if (b < NLEAD) {
            const u64* lp = &leaf[slot * NB + b * NCH + t];  // 1 child per lane
            u64 w;
            for (;;) {
                w = LDF(lp);
                if ((int)(w >> 32) >= phase) break;
                __builtin_amdgcn_s_sleep(1);
            }
            float x = __uint_as_float((unsigned)w);
            for (int o = 32; o; o >>= 1) x = __fadd_rn(x, __shfl_down(x, o, 64));
            if (t == 0) {
                u64 lw = ((u64)(unsigned)phase << 32) | (u64)__float_as_uint(x);
                __hip_atomic_store(&lead[slot * NLEAD + b], lw, __ATOMIC_RELAXED,
                                   __HIP_MEMORY_SCOPE_AGENT);
            }
        }
        const u64* gp = &lead[slot * NLEAD + (t & 7)];   // 8 flags, one 64B line
        u64 w;
        for (;;) {
            w = LDF(gp);
            if (__all((int)(w >> 32) >= phase)) break;
            __builtin_amdgcn_s_sleep(1);
        }
        float pay = __uint_as_float((unsigned)w);
        lsum = __shfl(pay, 0, 64);
        lsum = __fadd_rn(lsum, __shfl(pay, 1, 64));
        lsum = __fadd_rn(lsum, __shfl(pay, 2, 64));
        lsum = __fadd_rn(lsum, __shfl(pay, 3, 64));
        lsum = __fadd_rn(lsum, __shfl(pay, 4, 64));
        lsum = __fadd_rn(lsum, __shfl(pay, 5, 64));
        lsum = __fadd_rn(lsum, __shfl(pay, 6, 64));
        lsum = __fadd_rn(lsum, __shfl(pay, 7, 64));
    }
    __syncthreads();
    return lsum;
}

__global__ __launch_bounds__(NT, 4)
void sor_kernel(const float* __restrict__ img, const int* __restrict__ sinkp,
                float* __restrict__ v, int* __restrict__ listB, int* __restrict__ listR,
                u64* __restrict__ leaf, u64* __restrict__ lead,
                float* __restrict__ out)
{
    cg::grid_group grid = cg::this_grid();
    const int t   = (int)threadIdx.x;
    const int b   = (int)blockIdx.x;
    const int tid = b * NT + t;
    const float wopt  = (float)(2.0 / (1.0 + 3.14159265358979323846 / 130.0));
    const float sinkf = (float)(*sinkp);

    __shared__ float slab[CH];          // block-local mirror of own cells (16KB)
    __shared__ int   sB[NT], sR[NT];
    __shared__ float s4[4];
    __shared__ int   shN[2];            // cntB_local, cntR_local

    if (t == 0) {   // reset flag slots; ordered by the cg grid.sync() below
        __hip_atomic_store(&leaf[b],      0ull, __ATOMIC_RELAXED, __HIP_MEMORY_SCOPE_AGENT);
        __hip_atomic_store(&leaf[NB + b], 0ull, __ATOMIC_RELAXED, __HIP_MEMORY_SCOPE_AGENT);
        if (b < NLEAD) {
            __hip_atomic_store(&lead[b],         0ull, __ATOMIC_RELAXED, __HIP_MEMORY_SCOPE_AGENT);
            __hip_atomic_store(&lead[NLEAD + b], 0ull, __ATOMIC_RELAXED, __HIP_MEMORY_SCOPE_AGENT);
        }
    }

    // ---- init padded v: sink -> 1, else 0 ----
    for (int p = tid; p < NPAD; p += TOT) {
        int i = p / P2;
        int r = p - i * P2;
        int j = r / P;
        int k = r - j * P;
        float vv = 0.0f;
        if (i > 0 && i < P - 1 && j > 0 && j < P - 1 && k > 0 && k < P - 1) {
            float lab = img[(i - 1) * GG + (j - 1) * G + (k - 1)];
            vv = (lab == sinkf) ? 1.0f : 0.0f;
        }
        v[p] = vv;
    }

    // ---- zero the LDS slab (gm cells start at exactly 0) ----
    for (int x = t; x < CH; x += NT) slab[x] = 0.0f;

    // ---- per-thread active counts over contiguous 16-cell chunk ----
    const int g0 = b * CH + t * (CH / NT);
    int cB = 0, cR = 0;
    for (int q = 0; q < CH / NT; ++q) {
        float lab = img[g0 + q];
        if (lab == 1.0f) {
            int g = g0 + q;
            int par = ((g >> 14) + ((g >> 7) & 127) + (g & 127)) & 1;
            if (par) cB++; else cR++;
        }
    }
    sB[t] = cB; sR[t] = cR;
    __syncthreads();
    for (int off = 1; off < NT; off <<= 1) {
        int aB = 0, aR = 0;
        if (t >= off) { aB = sB[t - off]; aR = sR[t - off]; }
        __syncthreads();
        if (t >= off) { sB[t] += aB; sR[t] += aR; }
        __syncthreads();
    }
    const int exB = sB[t] - cB;
    const int exR = sR[t] - cR;
    if (t == NT - 1) { shN[0] = sB[t]; shN[1] = sR[t]; }
    __syncthreads();
    const int cntB = shN[0], cntR = shN[1];

    // ---- write block-local compacted lists (local idx l in [0,CH)) ----
    {
        int pB = exB, pR = exR;
        for (int q = 0; q < CH / NT; ++q) {
            int g = g0 + q;
            float lab = img[g];
            if (lab == 1.0f) {
                int l = t * (CH / NT) + q;
                int i = g >> 14, j = (g >> 7) & 127, k = g & 127;
                if ((i + j + k) & 1) { if (pB < SEG) listB[b * SEG + pB] = l; pB++; }
                else                 { if (pR < SEG) listR[b * SEG + pR] = l; pR++; }
            }
        }
    }
    __syncthreads();

    grid.sync();   // full fence: v init + flag resets globally visible, caches clean
    // From here on, v is touched ONLY via bypass (agent-scope) ops.

    // ---- hoist cells: msk bits say where each neighbor lives ----
    // bit0/1: k+1/k-1 gm (always same-slab -> LDS)
    // bit2/3: j+1/j-1 gm same-slab -> LDS     bit4/5: j+1/j-1 gm cross-slab -> v
    // bit6/7: i+1/i-1 gm (always cross-slab -> v)
    // ss = sum of frozen (non-gm) neighbor values = count of sink neighbors
#define HOIST(LIST, CNT, X, PV, LV, MV, SV)                                 \
    {                                                                       \
        PV = -1; LV = 0; MV = 0; SV = 0.0f;                                 \
        if ((X) < (CNT)) {                                                  \
            const int l = LIST[b * SEG + (X)]; LV = l;                      \
            const int g = b * CH + l;                                       \
            const int i = g >> 14, j = (g >> 7) & 127, k = g & 127;         \
            PV = (i + 1) * P2 + (j + 1) * P + (k + 1);                      \
            int m = 0; float ss = 0.0f; float lb;                           \
            if (k < 127) { lb = img[g + 1];                                 \
                if (lb == 1.0f) m |= 1;                                     \
                else ss = __fadd_rn(ss, (lb == sinkf) ? 1.0f : 0.0f); }     \
            if (k > 0)   { lb = img[g - 1];                                 \
                if (lb == 1.0f) m |= 2;                                     \
                else ss = __fadd_rn(ss, (lb == sinkf) ? 1.0f : 0.0f); }     \
            if (j < 127) { lb = img[g + G];                                 \
                if (lb == 1.0f) m |= ((j & 31) != 31) ? 4 : 16;             \
                else ss = __fadd_rn(ss, (lb == sinkf) ? 1.0f : 0.0f); }     \
            if (j > 0)   { lb = img[g - G];                                 \
                if (lb == 1.0f) m |= ((j & 31) != 0) ? 8 : 32;              \
                else ss = __fadd_rn(ss, (lb == sinkf) ? 1.0f : 0.0f); }     \
            if (i < 127) { lb = img[g + GG];                                \
                if (lb == 1.0f) m |= 64;                                    \
                else ss = __fadd_rn(ss, (lb == sinkf) ? 1.0f : 0.0f); }     \
            if (i > 0)   { lb = img[g - GG];                                \
                if (lb == 1.0f) m |= 128;                                   \
                else ss = __fadd_rn(ss, (lb == sinkf) ? 1.0f : 0.0f); }     \
            MV = m; SV = ss;                                                \
        }                                                                   \
    }

    int pB0, lB0, mB0; float sB0;
    int pB1, lB1, mB1; float sB1;
    int pB2, lB2, mB2; float sB2;
    int pR0, lR0, mR0; float sR0;
    int pR1, lR1, mR1; float sR1;
    int pR2, lR2, mR2; float sR2;
    HOIST(listB, cntB, t,          pB0, lB0, mB0, sB0)
    HOIST(listB, cntB, t + NT,     pB1, lB1, mB1, sB1)
    HOIST(listB, cntB, t + 2 * NT, pB2, lB2, mB2, sB2)
    HOIST(listR, cntR, t,          pR0, lR0, mR0, sR0)
    HOIST(listR, cntR, t + NT,     pR1, lR1, mR1, sR1)
    HOIST(listR, cntR, t + 2 * NT, pR2, lR2, mR2, sR2)

    // centers in registers: gm cells start at exactly 0; only this thread writes.
    float vB0 = 0.0f, vB1 = 0.0f, vB2 = 0.0f;
    float vR0 = 0.0f, vR1 = 0.0f, vR2 = 0.0f;

    // exact reference order (+1,-1,+P,-P,+P2,-P2) with exact +0 for non-gm
    // slots: bit-identical to the round-8 compacted sum. In-loop v-store only
    // when a cross-block gm reader exists (msk & 0xF0; adjacency is symmetric).
#define CELLS(PV, LV, MV, SV, V, loc)                                       \
    {                                                                       \
        float xk1 = slab[(LV + 1) & (CH - 1)];                              \
        float xk0 = slab[(LV - 1) & (CH - 1)];                              \
        float xj1 = slab[(LV + G) & (CH - 1)];                              \
        float xj0 = slab[(LV - G) & (CH - 1)];                              \
        float a0 = (MV & 1) ? xk1 : 0.0f;                                   \
        float a1 = (MV & 2) ? xk0 : 0.0f;                                   \
        float a2 = (MV & 4) ? xj1 : ((MV & 16) ? LDV(&v[PV + P]) : 0.0f);   \
        float a3 = (MV & 8) ? xj0 : ((MV & 32) ? LDV(&v[PV - P]) : 0.0f);   \
        float a4 = (MV & 64)  ? LDV(&v[PV + P2]) : 0.0f;                    \
        float a5 = (MV & 128) ? LDV(&v[PV - P2]) : 0.0f;                    \
        float s = __fadd_rn(a0, a1);                                        \
        s = __fadd_rn(s, a2); s = __fadd_rn(s, a3);                         \
        s = __fadd_rn(s, a4); s = __fadd_rn(s, a5);                         \
        s = __fadd_rn(s, SV);                                               \
        float tt = __fsub_rn(s, __fmul_rn(6.0f, V));                        \
        float adj = __fdiv_rn(__fmul_rn(wopt, tt), 6.0f);                   \
        V = __fadd_rn(V, adj);                                              \
        if (PV >= 0) {                                                      \
            slab[LV] = V;                                                   \
            if (MV & 0xF0) STV(&v[PV], V);                                  \
        }                                                                   \
        loc = __fadd_rn(loc, fabsf(adj));                                   \
    }

    int it = 0;
    float dv = 0.0f;
    int phase = 0;
    do {
        // ---------- black ----------
        float locb = 0.0f;
        CELLS(pB0, lB0, mB0, sB0, vB0, locb)
        CELLS(pB1, lB1, mB1, sB1, vB1, locb)
        CELLS(pB2, lB2, mB2, sB2, vB2, locb)
        float bs = bred(locb, t, s4);
        ++phase;
        float bacc = gbar2(leaf, lead, phase, b, t, bs);   // global black sum

        // ---------- red ----------
        float locr = 0.0f;
        CELLS(pR0, lR0, mR0, sR0, vR0, locr)
        CELLS(pR1, lR1, mR1, sR1, vR1, locr)
        CELLS(pR2, lR2, mR2, sR2, vR2, locr)
        float rs = bred(locr, t, s4);
        ++phase;
        float racc = gbar2(leaf, lead, phase, b, t, rs);   // global red sum

        // ---------- dv = blackSum + redSum, broadcast ----------
        if (t == 0) s4[0] = __fadd_rn(bacc, racc);
        __syncthreads();
        dv = s4[0];          // identical in every block (fixed order)

        ++it;
    } while (dv >= 0.05f && it <= 500);

    // cells with no cross-block reader were never stored to v: flush once,
    // then one more barrier so every block sees all final values.
    if (pB0 >= 0 && !(mB0 & 0xF0)) STV(&v[pB0], vB0);
    if (pB1 >= 0 && !(mB1 & 0xF0)) STV(&v[pB1], vB1);
    if (pB2 >= 0 && !(mB2 & 0xF0)) STV(&v[pB2], vB2);
    if (pR0 >= 0 && !(mR0 & 0xF0)) STV(&v[pR0], vR0);
    if (pR1 >= 0 && !(mR1 & 0xF0)) STV(&v[pR1], vR1);
    if (pR2 >= 0 && !(mR2 & 0xF0)) STV(&v[pR2], vR2);
    ++phase;
    gbar2(leaf, lead, phase, b, t, 0.0f);

    // ---- epilogue (v read via bypass: caches hold no valid v lines) ----
    for (int g = tid; g < NG; g += TOT) {
        int i = g >> 14, j = (g >> 7) & 127, k = g & 127;
        out[g] = LDV(&v[(i + 1) * P2 + (j + 1) * P + (k + 1)]);
    }
    if (tid == 0) {
        out[NG]     = (float)it;
        out[NG + 1] = dv;
    }
}

extern "C" void kernel_launch(void* const* d_in, const int* in_sizes, int n_in,
                              void* d_out, int out_size, void* d_ws, size_t ws_size,
                              hipStream_t stream) {
    const float* img  = (const float*)d_in[0];
    const int*   sink = (const int*)d_in[2];   // sink_label (=3)
    float*       out  = (float*)d_out;

    char* ws = (char*)d_ws;
    size_t off = 0;
    float* v = (float*)(ws + off);
    off += (size_t)NPAD * sizeof(float);
    off = (off + 255) & ~(size_t)255;
    int* listB = (int*)(ws + off);
    off += (size_t)NB * SEG * sizeof(int);
    int* listR = (int*)(ws + off);
    off += (size_t)NB * SEG * sizeof(int);
    off = (off + 255) & ~(size_t)255;
    u64* leaf = (u64*)(ws + off);
    off += (size_t)2 * NB * sizeof(u64);
    off = (off + 255) & ~(size_t)255;
    u64* lead = (u64*)(ws + off);
    off += (size_t)2 * NLEAD * sizeof(u64);
    (void)ws_size; (void)in_sizes; (void)n_in; (void)out_size;

    void* args[] = { (void*)&img, (void*)&sink, (void*)&v,
                     (void*)&listB, (void*)&listR,
                     (void*)&leaf, (void*)&lead, (void*)&out };
    hipLaunchCooperativeKernel((const void*)sor_kernel, dim3(NB), dim3(NT),
                               args, 0, stream);
}